// Round 3
// baseline (439.763 us; speedup 1.0000x reference)
//
#include <hip/hip_runtime.h>

typedef __attribute__((ext_vector_type(8))) short short8;
typedef __attribute__((ext_vector_type(4))) float f32x4;

#define C_DIM 512
#define S_DIM 4096
#define NCOL 165      // 3 * sum(k=1..10)
#define NCOLP 176     // padded to 11 * 16
#define LDK 40        // A LDS k-stride (shorts): 20-word rows -> conflict-free b128 frags
#define M_OUT 64
#define BK 32
#define NCHUNK 16     // 512 / 32
#define YST 180       // epilogue Y row stride (words): breaks 4-way quad conflicts (176%32==16 path)
#define YSLOT 2880    // 16 * YST

__device__ __forceinline__ unsigned short f2bf(float f) {
  unsigned u = __builtin_bit_cast(unsigned, f);
  u += 0x7fffu + ((u >> 16) & 1u);          // RNE (no NaN in data)
  return (unsigned short)(u >> 16);
}
__device__ __forceinline__ float bf2f(unsigned short h) {
  unsigned u = ((unsigned)h) << 16;
  return __builtin_bit_cast(float, u);
}

struct WP { const float* w[10]; };

// Pack weights into B^T layout: bt[col][c], col = 3*k(k-1)/2 + t*3 + p, split hi/lo bf16.
__global__ __launch_bounds__(256) void prep_kernel(WP wp, unsigned short* bt_hi,
                                                   unsigned short* bt_lo) {
  int idx = blockIdx.x * 256 + threadIdx.x;   // 176*512 threads exactly
  int col = idx >> 9;
  int c = idx & 511;
  float v = 0.f;
  if (col < NCOL) {
    int kw = 1, base = 0;
    while (col >= base + 3 * kw) { base += 3 * kw; ++kw; }
    int rem = col - base;
    int t = rem / 3, p = rem - 3 * t;
    v = wp.w[kw - 1][(t * C_DIM + c) * 3 + p];   // w_k layout (k, C, P)
  }
  unsigned short hi = f2bf(v);
  unsigned short lo = f2bf(v - bf2f(hi));
  bt_hi[col * C_DIM + c] = hi;
  bt_lo[col * C_DIM + c] = lo;
}

// fp32x4 -> packed bf16 hi pair + lo pair, RNE both (identical numerics to v1)
__device__ __forceinline__ void cvt_pack(const float4 v, uint2& hi, uint2& lo) {
  unsigned u0 = __builtin_bit_cast(unsigned, v.x);
  unsigned u1 = __builtin_bit_cast(unsigned, v.y);
  unsigned u2 = __builtin_bit_cast(unsigned, v.z);
  unsigned u3 = __builtin_bit_cast(unsigned, v.w);
  unsigned r0 = u0 + 0x7fffu + ((u0 >> 16) & 1u);
  unsigned r1 = u1 + 0x7fffu + ((u1 >> 16) & 1u);
  unsigned r2 = u2 + 0x7fffu + ((u2 >> 16) & 1u);
  unsigned r3 = u3 + 0x7fffu + ((u3 >> 16) & 1u);
  hi.x = __builtin_amdgcn_perm(r1, r0, 0x07060302u);
  hi.y = __builtin_amdgcn_perm(r3, r2, 0x07060302u);
  float m0 = v.x - __builtin_bit_cast(float, r0 & 0xffff0000u);
  float m1 = v.y - __builtin_bit_cast(float, r1 & 0xffff0000u);
  float m2 = v.z - __builtin_bit_cast(float, r2 & 0xffff0000u);
  float m3 = v.w - __builtin_bit_cast(float, r3 & 0xffff0000u);
  unsigned w0 = __builtin_bit_cast(unsigned, m0); w0 += 0x7fffu + ((w0 >> 16) & 1u);
  unsigned w1 = __builtin_bit_cast(unsigned, m1); w1 += 0x7fffu + ((w1 >> 16) & 1u);
  unsigned w2 = __builtin_bit_cast(unsigned, m2); w2 += 0x7fffu + ((w2 >> 16) & 1u);
  unsigned w3 = __builtin_bit_cast(unsigned, m3); w3 += 0x7fffu + ((w3 >> 16) & 1u);
  lo.x = __builtin_amdgcn_perm(w1, w0, 0x07060302u);
  lo.y = __builtin_amdgcn_perm(w3, w2, 0x07060302u);
}

__global__ __launch_bounds__(256, 4) void conv_kernel(const float* __restrict__ x,
                                                      const unsigned short* __restrict__ bt_hi,
                                                      const unsigned short* __restrict__ bt_lo,
                                                      float* __restrict__ out) {
  // LDS: A double buffer, hi/lo 80*40*2B = 6400 each -> 12800/buf, 25600 total.
  // Epilogue overlays front 23040 B as 2 slots of 16 x YST fp32.
  __shared__ __align__(16) unsigned char smem[25600];
  float* Ys = (float*)smem;

  const int tid = threadIdx.x;
  const int b = blockIdx.x >> 6;        // 64 tiles per batch
  const int tile = blockIdx.x & 63;
  const int s0 = tile * M_OUT;
  const int sBase = s0 - 16;            // halo start
  const int wave = tid >> 6;
  const int lane = tid & 63;
  const int lane15 = lane & 15;
  const int quad = lane >> 4;
  const int n0 = wave * 3;              // n-tile split 3/3/3/2
  const int nmine = (wave < 3) ? 3 : 2;

  // --- per-wave B fragment pointers (global, L2/L1-resident; no LDS, no barriers) ---
  const short8* bph[3];
  const short8* bpl[3];
#pragma unroll
  for (int nn = 0; nn < 3; ++nn) {
    int cr = (n0 + nn) * 16 + lane15;
    if (nn < nmine) {
      bph[nn] = (const short8*)&bt_hi[cr * C_DIM + quad * 8];
      bpl[nn] = (const short8*)&bt_lo[cr * C_DIM + quad * 8];
    } else {
      bph[nn] = (const short8*)&bt_hi[quad * 8];   // unused, keep in-bounds
      bpl[nn] = (const short8*)&bt_lo[quad * 8];
    }
  }

  // --- per-thread A staging geometry (640 float4 slots over 256 threads: 2.5 each) ---
  const float4* aptr[3];
  bool aexists[3], avalid[3];
  int arow[3], aq[3];
#pragma unroll
  for (int i = 0; i < 3; ++i) {
    int idx = tid + i * 256;
    aexists[i] = (idx < 640);
    arow[i] = idx >> 3;
    aq[i] = idx & 7;
    int s = sBase + arow[i];
    avalid[i] = aexists[i] && (s >= 0);
    aptr[i] = (const float4*)&x[((size_t)(b * S_DIM + (s < 0 ? 0 : s))) * C_DIM + aq[i] * 4];
  }

  float4 pf[3];
  f32x4 acc[5][3];
#pragma unroll
  for (int m = 0; m < 5; ++m)
#pragma unroll
    for (int n = 0; n < 3; ++n) acc[m][n] = (f32x4){0.f, 0.f, 0.f, 0.f};

  auto loadA = [&](int ch) {
#pragma unroll
    for (int i = 0; i < 3; ++i) {
      if (avalid[i]) pf[i] = aptr[i][ch * 8];          // ch*32 floats = ch*8 float4
      else pf[i] = make_float4(0.f, 0.f, 0.f, 0.f);
    }
  };
  auto cvtWrite = [&](int buf) {
    unsigned short* Ah = (unsigned short*)(smem + buf * 12800);
    unsigned short* Al = (unsigned short*)(smem + buf * 12800 + 6400);
#pragma unroll
    for (int i = 0; i < 3; ++i) {
      if (aexists[i]) {
        uint2 hi, lo;
        cvt_pack(pf[i], hi, lo);
        *(uint2*)&Ah[arow[i] * LDK + aq[i] * 4] = hi;
        *(uint2*)&Al[arow[i] * LDK + aq[i] * 4] = lo;
      }
    }
  };

  // ---------- prologue ----------
  loadA(0);
  cvtWrite(0);
  loadA(1);
  __syncthreads();

  for (int ch = 0; ch < NCHUNK; ++ch) {
    const unsigned short* Ah = (const unsigned short*)(smem + (ch & 1) * 12800);
    const unsigned short* Al = (const unsigned short*)(smem + (ch & 1) * 12800 + 6400);
    // B frags for this chunk: global loads (L2-hit), issued before LDS reads
    short8 bh[3], bl[3];
#pragma unroll
    for (int nn = 0; nn < 3; ++nn) {
      if (nn < nmine) {
        bh[nn] = bph[nn][ch * 4];      // ch*32 shorts = ch*4 short8
        bl[nn] = bpl[nn][ch * 4];
      }
    }
#pragma unroll
    for (int m = 0; m < 5; ++m) {
      int ar = m * 16 + lane15;
      short8 ah = *(const short8*)&Ah[ar * LDK + quad * 8];
      short8 al = *(const short8*)&Al[ar * LDK + quad * 8];
#pragma unroll
      for (int nn = 0; nn < 3; ++nn) {
        if (nn < nmine) {
          acc[m][nn] = __builtin_amdgcn_mfma_f32_16x16x32_bf16(ah, bh[nn], acc[m][nn], 0, 0, 0);
          acc[m][nn] = __builtin_amdgcn_mfma_f32_16x16x32_bf16(ah, bl[nn], acc[m][nn], 0, 0, 0);
          acc[m][nn] = __builtin_amdgcn_mfma_f32_16x16x32_bf16(al, bh[nn], acc[m][nn], 0, 0, 0);
        }
      }
    }
    if (ch < NCHUNK - 1) {
      cvtWrite((ch + 1) & 1);          // pf(ch+1) loaded a full chunk ago -> latency hidden
      if (ch < NCHUNK - 2) loadA(ch + 2);
    }
    __syncthreads();                   // single barrier per chunk (LDS-only dependency)
  }

  // ---- epilogue: d-sum + relu via LDS, ping-pong 16 x YST fp32 slots ----
  // C/D layout: col = lane&15 (global col = (n0+nn)*16 + lane15), row = quad*4 + reg.
#pragma unroll
  for (int i = 1; i <= 4; ++i) {
    if (i == 1) {
#pragma unroll
      for (int nn = 0; nn < 3; ++nn)
        if (nn < nmine)
#pragma unroll
          for (int r = 0; r < 4; ++r)
            Ys[0 * YSLOT + (quad * 4 + r) * YST + (n0 + nn) * 16 + lane15] = acc[0][nn][r];
    }
#pragma unroll
    for (int nn = 0; nn < 3; ++nn)
      if (nn < nmine)
#pragma unroll
        for (int r = 0; r < 4; ++r)
          Ys[(i & 1) * YSLOT + (quad * 4 + r) * YST + (n0 + nn) * 16 + lane15] = acc[i][nn][r];
    __syncthreads();
    for (int o = tid; o < 480; o += 256) {
      int r = o / 30;
      int j = o - 30 * r;
      int kw = j / 3 + 1;
      int p = j - (kw - 1) * 3;
      int base = 3 * (kw * (kw - 1)) / 2;
      float sum = 0.f;
      for (int d = 0; d < kw; ++d) {
        int rr = r - d;
        int slot = (rr >= 0) ? (i & 1) : ((i ^ 1) & 1);
        int lr = (rr >= 0) ? rr : (16 + rr);
        int colv = base + (kw - 1 - d) * 3 + p;
        sum += Ys[slot * YSLOT + lr * YST + colv];
      }
      int s = s0 + 16 * (i - 1) + r;
      out[((size_t)(b * S_DIM + s)) * 30 + j] = fmaxf(sum, 0.f);
    }
    __syncthreads();
  }
}

extern "C" void kernel_launch(void* const* d_in, const int* in_sizes, int n_in,
                              void* d_out, int out_size, void* d_ws, size_t ws_size,
                              hipStream_t stream) {
  const float* x = (const float*)d_in[0];
  WP wp;
  for (int k = 0; k < 10; ++k) wp.w[k] = (const float*)d_in[k + 1];
  unsigned short* bt_hi = (unsigned short*)d_ws;
  unsigned short* bt_lo = bt_hi + NCOLP * C_DIM;   // +180224 bytes
  prep_kernel<<<NCOLP * C_DIM / 256, 256, 0, stream>>>(wp, bt_hi, bt_lo);
  conv_kernel<<<32 * (S_DIM / M_OUT), 256, 0, stream>>>(x, bt_hi, bt_lo, (float*)d_out);
}

// Round 4
// 417.473 us; speedup vs baseline: 1.0534x; 1.0534x over previous
//
#include <hip/hip_runtime.h>

typedef _Float16 half8 __attribute__((ext_vector_type(8)));
typedef _Float16 half4 __attribute__((ext_vector_type(4)));
typedef __attribute__((ext_vector_type(4))) float f32x4;

#define C_DIM 512
#define S_DIM 4096
#define NCOL 165      // 3 * sum(k=1..10)
#define NCOLP 176     // padded to 11 * 16
#define LDK 40        // A LDS k-stride (halves): 20-word rows -> conflict-even b128 frags
#define M_OUT 64
#define BK 32
#define NCHUNK 16     // 512 / 32
#define YST 180       // epilogue Y row stride (words): quad stride 720%32=16 -> 2-way (free)
#define YSLOT 2880    // 16 * YST

struct WP { const float* w[10]; };

// Pack weights into B^T fp16: bt[col][c], col = 3*k(k-1)/2 + t*3 + p. RNE cast.
__global__ __launch_bounds__(256) void prep_kernel(WP wp, _Float16* bt) {
  int idx = blockIdx.x * 256 + threadIdx.x;   // 176*512 threads exactly
  int col = idx >> 9;
  int c = idx & 511;
  float v = 0.f;
  if (col < NCOL) {
    int kw = 1, base = 0;
    while (col >= base + 3 * kw) { base += 3 * kw; ++kw; }
    int rem = col - base;
    int t = rem / 3, p = rem - 3 * t;
    v = wp.w[kw - 1][(t * C_DIM + c) * 3 + p];   // w_k layout (k, C, P)
  }
  bt[col * C_DIM + c] = (_Float16)v;
}

// LDS-visibility-only barrier: does NOT drain vmcnt — global loads stay in flight
// across the barrier (AITER-style). Safe here: cross-wave deps are LDS-only.
__device__ __forceinline__ void barrier_lgkm() {
  __asm__ volatile("s_waitcnt lgkmcnt(0)\n\ts_barrier" ::: "memory");
}

__global__ __launch_bounds__(256, 4) void conv_kernel(const float* __restrict__ x,
                                                      const _Float16* __restrict__ bt,
                                                      float* __restrict__ out) {
  // LDS: A fp16 double buffer, 80*40*2B = 6400/buf -> 12800 total.
  // Epilogue overlays [0,23040) as 2 slots of 16 x YST fp32.
  __shared__ __align__(16) unsigned char smem[23040];
  float* Ys = (float*)smem;

  const int tid = threadIdx.x;
  const int b = blockIdx.x >> 6;        // 64 tiles per batch
  const int tile = blockIdx.x & 63;
  const int s0 = tile * M_OUT;
  const int sBase = s0 - 16;            // halo start
  const int wave = tid >> 6;
  const int lane = tid & 63;
  const int lane15 = lane & 15;
  const int quad = lane >> 4;
  const int n0 = wave * 3;              // n-tile split 3/3/3/2
  const int nmine = (wave < 3) ? 3 : 2;

  // --- per-wave B fragment pointers (global, L2-resident; register double-buffered) ---
  const half8* bptr[3];
#pragma unroll
  for (int nn = 0; nn < 3; ++nn) {
    int cr = (n0 + nn) * 16 + lane15;
    bptr[nn] = (const half8*)&bt[(nn < nmine ? cr : lane15) * C_DIM + quad * 8];
  }

  // --- per-thread A staging geometry (640 float4 slots over 256 threads: 2.5 each) ---
  const float4* aptr[3];
  bool aexists[3], avalid[3];
  int arow[3], aq[3];
#pragma unroll
  for (int i = 0; i < 3; ++i) {
    int idx = tid + i * 256;
    aexists[i] = (idx < 640);
    arow[i] = idx >> 3;
    aq[i] = idx & 7;
    int s = sBase + arow[i];
    avalid[i] = aexists[i] && (s >= 0);
    aptr[i] = (const float4*)&x[((size_t)(b * S_DIM + (s < 0 ? 0 : s))) * C_DIM + aq[i] * 4];
  }

  float4 pf[3];
  half8 bcur[3], bnxt[3];
  f32x4 acc[5][3];
#pragma unroll
  for (int m = 0; m < 5; ++m)
#pragma unroll
    for (int n = 0; n < 3; ++n) acc[m][n] = (f32x4){0.f, 0.f, 0.f, 0.f};

  auto loadA = [&](int ch) {
#pragma unroll
    for (int i = 0; i < 3; ++i) {
      if (avalid[i]) pf[i] = aptr[i][ch * 8];          // ch*32 floats = ch*8 float4
      else pf[i] = make_float4(0.f, 0.f, 0.f, 0.f);
    }
  };
  auto cvtWrite = [&](int buf) {
    _Float16* Ah = (_Float16*)(smem + buf * 6400);
#pragma unroll
    for (int i = 0; i < 3; ++i) {
      if (aexists[i]) {
        half4 h = {(_Float16)pf[i].x, (_Float16)pf[i].y,
                   (_Float16)pf[i].z, (_Float16)pf[i].w};   // RNE casts
        *(half4*)&Ah[arow[i] * LDK + aq[i] * 4] = h;
      }
    }
  };

  // ---------- prologue: stage chunk 0 (A in LDS, B in regs), prefetch A(1) ----------
  loadA(0);
  cvtWrite(0);
#pragma unroll
  for (int nn = 0; nn < 3; ++nn)
    if (nn < nmine) bcur[nn] = bptr[nn][0];
  loadA(1);
  barrier_lgkm();

#pragma unroll
  for (int ch = 0; ch < NCHUNK; ++ch) {
    // prefetch next B frags (consumed next iteration; lands during MFMAs below)
    if (ch < NCHUNK - 1) {
#pragma unroll
      for (int nn = 0; nn < 3; ++nn)
        if (nn < nmine) bnxt[nn] = bptr[nn][(ch + 1) * 4];
    }
    const _Float16* Ah = (const _Float16*)(smem + (ch & 1) * 6400);
#pragma unroll
    for (int m = 0; m < 5; ++m) {
      half8 a = *(const half8*)&Ah[(m * 16 + lane15) * LDK + quad * 8];
#pragma unroll
      for (int nn = 0; nn < 3; ++nn)
        if (nn < nmine)
          acc[m][nn] = __builtin_amdgcn_mfma_f32_16x16x32_f16(a, bcur[nn], acc[m][nn], 0, 0, 0);
    }
    if (ch < NCHUNK - 1) {
      cvtWrite((ch + 1) & 1);            // pf(ch+1) was issued a full chunk ago
      if (ch < NCHUNK - 2) loadA(ch + 2);
#pragma unroll
      for (int nn = 0; nn < 3; ++nn)
        if (nn < nmine) bcur[nn] = bnxt[nn];
    }
    barrier_lgkm();                      // LDS-only drain: global loads stay in flight
  }

  // ---- epilogue: d-sum + relu via LDS, ping-pong 16 x YST fp32 slots ----
  // C/D layout: col = lane&15 (global col = (n0+nn)*16 + lane15), row = quad*4 + reg.
#pragma unroll
  for (int i = 1; i <= 4; ++i) {
    if (i == 1) {
#pragma unroll
      for (int nn = 0; nn < 3; ++nn)
        if (nn < nmine)
#pragma unroll
          for (int r = 0; r < 4; ++r)
            Ys[0 * YSLOT + (quad * 4 + r) * YST + (n0 + nn) * 16 + lane15] = acc[0][nn][r];
    }
#pragma unroll
    for (int nn = 0; nn < 3; ++nn)
      if (nn < nmine)
#pragma unroll
        for (int r = 0; r < 4; ++r)
          Ys[(i & 1) * YSLOT + (quad * 4 + r) * YST + (n0 + nn) * 16 + lane15] = acc[i][nn][r];
    __syncthreads();
    for (int o = tid; o < 480; o += 256) {
      int r = o / 30;
      int j = o - 30 * r;
      int kw = j / 3 + 1;
      int p = j - (kw - 1) * 3;
      int base = 3 * (kw * (kw - 1)) / 2;
      float sum = 0.f;
      for (int d = 0; d < kw; ++d) {
        int rr = r - d;
        int slot = (rr >= 0) ? (i & 1) : ((i ^ 1) & 1);
        int lr = (rr >= 0) ? rr : (16 + rr);
        int colv = base + (kw - 1 - d) * 3 + p;
        sum += Ys[slot * YSLOT + lr * YST + colv];
      }
      int s = s0 + 16 * (i - 1) + r;
      out[((size_t)(b * S_DIM + s)) * 30 + j] = fmaxf(sum, 0.f);
    }
    __syncthreads();
  }
}

extern "C" void kernel_launch(void* const* d_in, const int* in_sizes, int n_in,
                              void* d_out, int out_size, void* d_ws, size_t ws_size,
                              hipStream_t stream) {
  const float* x = (const float*)d_in[0];
  WP wp;
  for (int k = 0; k < 10; ++k) wp.w[k] = (const float*)d_in[k + 1];
  _Float16* bt = (_Float16*)d_ws;                  // 176*512*2 B = 180224 B
  prep_kernel<<<NCOLP * C_DIM / 256, 256, 0, stream>>>(wp, bt);
  conv_kernel<<<32 * (S_DIM / M_OUT), 256, 0, stream>>>(x, bt, (float*)d_out);
}

// Round 5
// 407.129 us; speedup vs baseline: 1.0802x; 1.0254x over previous
//
#include <hip/hip_runtime.h>

typedef _Float16 half8 __attribute__((ext_vector_type(8)));
typedef __attribute__((ext_vector_type(4))) float f32x4;

#define C_DIM 512
#define S_DIM 4096
#define NCOL 165      // 3 * sum(k=1..10)
#define NCOLP 176     // padded to 11 * 16
#define M_OUT 64
#define ROWS 80       // 16 halo + 64 output rows
#define BK 32
#define NCHUNK 16     // 512 / 32
#define RJ 9          // float4 slots per LDS row: 8 data + 1 pad (36-word stride, 2-way free)
#define BUFSZ 12288   // bytes per A buffer: 768 slots * 16B = 12 DMA instr * 1KB
#define YST 180       // epilogue Y row stride (words)
#define YSLOT 2880    // 16 * YST

struct WP { const float* w[10]; };

// Pack weights into B^T fp16: bt[col][c]; block 352 zeroes the 4KB halo zero-buffer.
__global__ __launch_bounds__(256) void prep_kernel(WP wp, _Float16* bt, float4* zbuf) {
  if (blockIdx.x == NCOLP * C_DIM / 256) {
    zbuf[threadIdx.x] = make_float4(0.f, 0.f, 0.f, 0.f);   // 256*16B = 4KB zeros
    return;
  }
  int idx = blockIdx.x * 256 + threadIdx.x;   // 176*512 threads exactly
  int col = idx >> 9;
  int c = idx & 511;
  float v = 0.f;
  if (col < NCOL) {
    int kw = 1, base = 0;
    while (col >= base + 3 * kw) { base += 3 * kw; ++kw; }
    int rem = col - base;
    int t = rem / 3, p = rem - 3 * t;
    v = wp.w[kw - 1][(t * C_DIM + c) * 3 + p];   // w_k layout (k, C, P)
  }
  bt[col * C_DIM + c] = (_Float16)v;            // RNE
}

__device__ __forceinline__ void gld16(const void* g, void* l) {
  __builtin_amdgcn_global_load_lds(
      (const __attribute__((address_space(1))) unsigned int*)(const unsigned int*)g,
      (__attribute__((address_space(3))) unsigned int*)(unsigned int*)l, 16, 0, 0);
}

// Keep the 3 newest vmem ops (next chunk's DMA) in flight; drain everything older.
__device__ __forceinline__ void wait_vm3() {
  __asm__ volatile("s_waitcnt vmcnt(3)" ::: "memory");
}
// LDS-visibility barrier: does NOT drain vmcnt (global/DMA ops stay in flight).
__device__ __forceinline__ void barrier_lgkm() {
  __asm__ volatile("s_waitcnt lgkmcnt(0)\n\ts_barrier" ::: "memory");
}

__global__ __launch_bounds__(256, 3) void conv_kernel(const float* __restrict__ x,
                                                      const _Float16* __restrict__ bt,
                                                      const float* __restrict__ zbuf,
                                                      float* __restrict__ out) {
  // LDS: 3 A-buffers (fp32, DMA-filled, 12KB each) = 36864 B.
  // Epilogue overlays [0, 23040) as 2 slots of 16 x YST fp32.
  __shared__ __align__(16) unsigned char smem[3 * BUFSZ];
  float* Ys = (float*)smem;

  const int tid = threadIdx.x;
  const int b = blockIdx.x >> 6;        // 64 tiles per batch
  const int tile = blockIdx.x & 63;
  const int s0 = tile * M_OUT;
  const int sBase = s0 - 16;            // halo start
  const int wave = tid >> 6;
  const int lane = tid & 63;
  const int l15 = lane & 15;
  const int quad = lane >> 4;
  const int wnu = __builtin_amdgcn_readfirstlane(wave);
  const int n0 = wave * 3;              // n-tile split 3/3/3/2
  const int nmine = (wave < 3) ? 3 : 2;

  // --- per-wave B fragment pointers (global, L1/L2-resident) ---
  const half8* bptr[3];
#pragma unroll
  for (int nn = 0; nn < 3; ++nn) {
    int cr = (n0 + nn) * 16 + l15;
    bptr[nn] = (const half8*)&bt[(nn < nmine ? cr : l15) * C_DIM + quad * 8];
  }

  // --- per-lane DMA source addresses (3 instructions per wave per chunk) ---
  // LDS slot sigma = t*64+lane holds row=sigma/9, float4 j=sigma%9 (j==8 is pad).
  const char* asrc[3];
#pragma unroll
  for (int i = 0; i < 3; ++i) {
    int t = wave * 3 + i;               // 0..11
    int sigma = t * 64 + lane;          // 0..767
    int row = sigma / RJ;
    int j = sigma - row * RJ;
    int s = sBase + row;
    bool ok = (j < 8) && (row < ROWS) && (s >= 0);
    asrc[i] = ok ? (const char*)&x[((size_t)(b * S_DIM + s)) * C_DIM + j * 4]
                 : (const char*)zbuf + lane * 16;  // zeros; +ch*128 stays <4KB
  }
  const int ldst = wnu * 3;             // wave's DMA instruction base (uniform)

  f32x4 acc[5][3];
#pragma unroll
  for (int m = 0; m < 5; ++m)
#pragma unroll
    for (int n = 0; n < 3; ++n) acc[m][n] = (f32x4){0.f, 0.f, 0.f, 0.f};

  // ---------- prologue: DMA chunks 0,1 into bufs 0,1; publish buf 0 ----------
#pragma unroll
  for (int i = 0; i < 3; ++i)
    gld16(asrc[i], smem + (ldst + i) * 1024);
#pragma unroll
  for (int i = 0; i < 3; ++i)
    gld16(asrc[i] + 128, smem + BUFSZ + (ldst + i) * 1024);
  wait_vm3();                           // buf0 DMA done; buf1 DMA still flying
  barrier_lgkm();

#pragma unroll
  for (int ch = 0; ch < NCHUNK; ++ch) {
    const int cb = ch % 3;
    const int nb = (ch + 2) % 3;
    // B frags for this chunk (L1/L2 hit; consumed after frag reads+cvt)
    half8 bfr[3];
#pragma unroll
    for (int nn = 0; nn < 3; ++nn)
      if (nn < nmine) bfr[nn] = bptr[nn][ch * 4];
    // async DMA for chunk ch+2 (lands ~2 chunks from now; never drained to 0)
    if (ch < NCHUNK - 2) {
#pragma unroll
      for (int i = 0; i < 3; ++i)
        gld16(asrc[i] + (ch + 2) * 128, smem + nb * BUFSZ + (ldst + i) * 1024);
    }
    // compute on buf cb: fp32 frags -> fp16 RNE -> MFMA
    const float* Af = (const float*)(smem + cb * BUFSZ);
#pragma unroll
    for (int m = 0; m < 5; ++m) {
      const float* rp = Af + (m * 16 + l15) * (RJ * 4) + quad * 8;
      f32x4 a0 = *(const f32x4*)rp;
      f32x4 a1 = *(const f32x4*)(rp + 4);
      half8 ah = {(_Float16)a0[0], (_Float16)a0[1], (_Float16)a0[2], (_Float16)a0[3],
                  (_Float16)a1[0], (_Float16)a1[1], (_Float16)a1[2], (_Float16)a1[3]};
#pragma unroll
      for (int nn = 0; nn < 3; ++nn)
        if (nn < nmine)
          acc[m][nn] = __builtin_amdgcn_mfma_f32_16x16x32_f16(ah, bfr[nn], acc[m][nn], 0, 0, 0);
    }
    wait_vm3();                         // drain DMA(ch+1) (publishes next buf); keep DMA(ch+2)
    barrier_lgkm();                     // LDS-only barrier: vmcnt never forced to 0
  }

  __syncthreads();                      // full drain before overlaying A bufs with Ys

  // ---- epilogue: d-sum + relu via LDS, ping-pong 16 x YST fp32 slots ----
  // C/D layout: col = lane&15 (global col = (n0+nn)*16 + l15), row = quad*4 + reg.
#pragma unroll
  for (int i = 1; i <= 4; ++i) {
    if (i == 1) {
#pragma unroll
      for (int nn = 0; nn < 3; ++nn)
        if (nn < nmine)
#pragma unroll
          for (int r = 0; r < 4; ++r)
            Ys[0 * YSLOT + (quad * 4 + r) * YST + (n0 + nn) * 16 + l15] = acc[0][nn][r];
    }
#pragma unroll
    for (int nn = 0; nn < 3; ++nn)
      if (nn < nmine)
#pragma unroll
        for (int r = 0; r < 4; ++r)
          Ys[(i & 1) * YSLOT + (quad * 4 + r) * YST + (n0 + nn) * 16 + l15] = acc[i][nn][r];
    __syncthreads();
    for (int o = tid; o < 480; o += 256) {
      int r = o / 30;
      int j = o - 30 * r;
      int kw = j / 3 + 1;
      int p = j - (kw - 1) * 3;
      int base = 3 * (kw * (kw - 1)) / 2;
      float sum = 0.f;
      for (int d = 0; d < kw; ++d) {
        int rr = r - d;
        int slot = (rr >= 0) ? (i & 1) : ((i ^ 1) & 1);
        int lr = (rr >= 0) ? rr : (16 + rr);
        int colv = base + (kw - 1 - d) * 3 + p;
        sum += Ys[slot * YSLOT + lr * YST + colv];
      }
      int s = s0 + 16 * (i - 1) + r;
      out[((size_t)(b * S_DIM + s)) * 30 + j] = fmaxf(sum, 0.f);
    }
    __syncthreads();
  }
}

extern "C" void kernel_launch(void* const* d_in, const int* in_sizes, int n_in,
                              void* d_out, int out_size, void* d_ws, size_t ws_size,
                              hipStream_t stream) {
  const float* x = (const float*)d_in[0];
  WP wp;
  for (int k = 0; k < 10; ++k) wp.w[k] = (const float*)d_in[k + 1];
  _Float16* bt = (_Float16*)d_ws;                                // 180224 B
  float4* zbuf = (float4*)((char*)d_ws + NCOLP * C_DIM * 2);     // 4 KB zeros
  prep_kernel<<<NCOLP * C_DIM / 256 + 1, 256, 0, stream>>>(wp, bt, zbuf);
  conv_kernel<<<32 * (S_DIM / M_OUT), 256, 0, stream>>>(x, bt, (const float*)zbuf,
                                                        (float*)d_out);
}

// Round 6
// 400.855 us; speedup vs baseline: 1.0971x; 1.0157x over previous
//
#include <hip/hip_runtime.h>

typedef _Float16 half8 __attribute__((ext_vector_type(8)));
typedef __attribute__((ext_vector_type(4))) float f32x4;

#define C_DIM 512
#define S_DIM 4096
#define NCOL 165      // 3 * sum(k=1..10)
#define NCOLP 176     // padded to 11 * 16
#define M_OUT 64
#define ROWS 80       // 16 halo + 64 output rows
#define BK 32
#define NCHUNK 16     // 512 / 32
#define RJ 9          // float4 slots per LDS row: 8 data + 1 pad (36-word stride, ~2-way free)
#define BUFSZ 12288   // bytes per A buffer: 768 slots * 16B = 12 DMA instr * 1KB
#define NBUF 4        // A buffers; DMA issued 3 chunks ahead
#define YST 180       // epilogue Y row stride (words)
#define YSLOT 2880    // 16 * YST

struct WP { const float* w[10]; };

// Pack weights into B^T fp16: bt[col][c]; last block zeroes the 4KB halo zero-buffer.
__global__ __launch_bounds__(256) void prep_kernel(WP wp, _Float16* bt, float4* zbuf) {
  if (blockIdx.x == NCOLP * C_DIM / 256) {
    zbuf[threadIdx.x] = make_float4(0.f, 0.f, 0.f, 0.f);   // 256*16B = 4KB zeros
    return;
  }
  int idx = blockIdx.x * 256 + threadIdx.x;   // 176*512 threads exactly
  int col = idx >> 9;
  int c = idx & 511;
  float v = 0.f;
  if (col < NCOL) {
    int kw = 1, base = 0;
    while (col >= base + 3 * kw) { base += 3 * kw; ++kw; }
    int rem = col - base;
    int t = rem / 3, p = rem - 3 * t;
    v = wp.w[kw - 1][(t * C_DIM + c) * 3 + p];   // w_k layout (k, C, P)
  }
  bt[col * C_DIM + c] = (_Float16)v;            // RNE
}

__device__ __forceinline__ void gld16(const void* g, void* l) {
  __builtin_amdgcn_global_load_lds(
      (const __attribute__((address_space(1))) unsigned int*)(const unsigned int*)g,
      (__attribute__((address_space(3))) unsigned int*)(unsigned int*)l, 16, 0, 0);
}

template <int N>
__device__ __forceinline__ void wait_vm() {
  __asm__ volatile("s_waitcnt vmcnt(%0)" ::"i"(N) : "memory");
}
// LDS-visibility barrier: does NOT drain vmcnt (DMA/global loads stay in flight).
__device__ __forceinline__ void barrier_lgkm() {
  __asm__ volatile("s_waitcnt lgkmcnt(0)\n\ts_barrier" ::: "memory");
}

__global__ __launch_bounds__(256, 3) void conv_kernel(const float* __restrict__ x,
                                                      const _Float16* __restrict__ bt,
                                                      const float* __restrict__ zbuf,
                                                      float* __restrict__ out) {
  // LDS: 4 A-buffers (fp32, DMA-filled 3-ahead, 12KB each) = 49152 B.
  // Epilogue overlays [0, 23040) as 2 slots of 16 x YST fp32.
  __shared__ __align__(16) unsigned char smem[NBUF * BUFSZ];
  float* Ys = (float*)smem;

  const int tid = threadIdx.x;
  const int b = blockIdx.x >> 6;        // 64 tiles per batch
  const int tile = blockIdx.x & 63;
  const int s0 = tile * M_OUT;
  const int sBase = s0 - 16;            // halo start
  const int wave = tid >> 6;
  const int lane = tid & 63;
  const int l15 = lane & 15;
  const int quad = lane >> 4;
  const int wnu = __builtin_amdgcn_readfirstlane(wave);
  const int n0 = wave * 3;              // n-tile split 3/3/3/2
  const int nmine = (wave < 3) ? 3 : 2;

  // --- per-wave B fragment pointers (global, L1/L2-resident) ---
  const half8* bptr[3];
#pragma unroll
  for (int nn = 0; nn < 3; ++nn) {
    int cr = (n0 + nn) * 16 + l15;
    bptr[nn] = (const half8*)&bt[(nn < nmine ? cr : l15) * C_DIM + quad * 8];
  }

  // --- per-lane DMA source addresses (3 instructions per wave per chunk) ---
  const char* asrc[3];
#pragma unroll
  for (int i = 0; i < 3; ++i) {
    int t = wave * 3 + i;               // 0..11
    int sigma = t * 64 + lane;          // 0..767
    int row = sigma / RJ;
    int j = sigma - row * RJ;
    int s = sBase + row;
    bool ok = (j < 8) && (row < ROWS) && (s >= 0);
    asrc[i] = ok ? (const char*)&x[((size_t)(b * S_DIM + s)) * C_DIM + j * 4]
                 : (const char*)zbuf + lane * 16;  // zeros; +ch*128 stays <4KB
  }
  const int ldst = wnu * 3;             // wave's DMA slot base (wave-uniform)

  f32x4 acc[5][3];
#pragma unroll
  for (int m = 0; m < 5; ++m)
#pragma unroll
    for (int n = 0; n < 3; ++n) acc[m][n] = (f32x4){0.f, 0.f, 0.f, 0.f};

  // ---------- prologue ----------
  // Issue order (oldest->newest): B0, B1, D0, D1, D2. Wait for D0 -> vmcnt(6):
  // drains B0,B1,D0; keeps D1,D2 in flight.
  half8 breg[3][3];                     // ring: slot ch%3 holds B(ch)
#pragma unroll
  for (int nn = 0; nn < 3; ++nn)
    if (nn < nmine) breg[0][nn] = bptr[nn][0];
#pragma unroll
  for (int nn = 0; nn < 3; ++nn)
    if (nn < nmine) breg[1][nn] = bptr[nn][4];
#pragma unroll
  for (int c = 0; c < 3; ++c)
#pragma unroll
    for (int i = 0; i < 3; ++i)
      gld16(asrc[i] + c * 128, smem + c * BUFSZ + (ldst + i) * 1024);
  wait_vm<6>();
  barrier_lgkm();

#pragma unroll
  for (int ch = 0; ch < NCHUNK; ++ch) {
    // B(ch+2) into ring slot (ch+2)%3 — issued BEFORE this chunk's DMA so that
    // MFMA(ch)'s implicit wait for B(ch) (issued 2 chunks ago) drains nothing newer.
    if (ch + 2 < NCHUNK) {
#pragma unroll
      for (int nn = 0; nn < 3; ++nn)
        if (nn < nmine) breg[(ch + 2) % 3][nn] = bptr[nn][(ch + 2) * 4];
    }
    // DMA(ch+3): lands 3 chunks from now; never force-drained early.
    if (ch + 3 < NCHUNK) {
#pragma unroll
      for (int i = 0; i < 3; ++i)
        gld16(asrc[i] + (ch + 3) * 128, smem + ((ch + 3) % NBUF) * BUFSZ + (ldst + i) * 1024);
    }
    // compute on buf ch%NBUF: fp32 frags -> fp16 RNE -> MFMA
    const float* Af = (const float*)(smem + (ch % NBUF) * BUFSZ);
#pragma unroll
    for (int m = 0; m < 5; ++m) {
      const float* rp = Af + (m * 16 + l15) * (RJ * 4) + quad * 8;
      f32x4 a0 = *(const f32x4*)rp;
      f32x4 a1 = *(const f32x4*)(rp + 4);
      half8 ah = {(_Float16)a0[0], (_Float16)a0[1], (_Float16)a0[2], (_Float16)a0[3],
                  (_Float16)a1[0], (_Float16)a1[1], (_Float16)a1[2], (_Float16)a1[3]};
#pragma unroll
      for (int nn = 0; nn < 3; ++nn)
        if (nn < nmine)
          acc[m][nn] =
              __builtin_amdgcn_mfma_f32_16x16x32_f16(ah, breg[ch % 3][nn], acc[m][nn], 0, 0, 0);
    }
    // End-of-chunk: drain exactly DMA(ch+1); keep {B(ch+1),D(ch+2),B(ch+2),D(ch+3)}.
    if (ch == 0) wait_vm<9>();
    else if (ch <= 12) wait_vm<12>();
    else if (ch == 13) wait_vm<9>();
    else if (ch == 14) wait_vm<3>();
    if (ch < NCHUNK - 1) barrier_lgkm();
  }

  __syncthreads();                      // full drain before overlaying A bufs with Ys

  // ---- epilogue: d-sum + relu via LDS, ping-pong 16 x YST fp32 slots ----
  // C/D layout: col = lane&15 (global col = (n0+nn)*16 + l15), row = quad*4 + reg.
#pragma unroll
  for (int i = 1; i <= 4; ++i) {
    if (i == 1) {
#pragma unroll
      for (int nn = 0; nn < 3; ++nn)
        if (nn < nmine)
#pragma unroll
          for (int r = 0; r < 4; ++r)
            Ys[0 * YSLOT + (quad * 4 + r) * YST + (n0 + nn) * 16 + l15] = acc[0][nn][r];
    }
#pragma unroll
    for (int nn = 0; nn < 3; ++nn)
      if (nn < nmine)
#pragma unroll
        for (int r = 0; r < 4; ++r)
          Ys[(i & 1) * YSLOT + (quad * 4 + r) * YST + (n0 + nn) * 16 + l15] = acc[i][nn][r];
    __syncthreads();
    for (int o = tid; o < 480; o += 256) {
      int r = o / 30;
      int j = o - 30 * r;
      int kw = j / 3 + 1;
      int p = j - (kw - 1) * 3;
      int base = 3 * (kw * (kw - 1)) / 2;
      float sum = 0.f;
      for (int d = 0; d < kw; ++d) {
        int rr = r - d;
        int slot = (rr >= 0) ? (i & 1) : ((i ^ 1) & 1);
        int lr = (rr >= 0) ? rr : (16 + rr);
        int colv = base + (kw - 1 - d) * 3 + p;
        sum += Ys[slot * YSLOT + lr * YST + colv];
      }
      int s = s0 + 16 * (i - 1) + r;
      out[((size_t)(b * S_DIM + s)) * 30 + j] = fmaxf(sum, 0.f);
    }
    __syncthreads();
  }
}

extern "C" void kernel_launch(void* const* d_in, const int* in_sizes, int n_in,
                              void* d_out, int out_size, void* d_ws, size_t ws_size,
                              hipStream_t stream) {
  const float* x = (const float*)d_in[0];
  WP wp;
  for (int k = 0; k < 10; ++k) wp.w[k] = (const float*)d_in[k + 1];
  _Float16* bt = (_Float16*)d_ws;                                // 180224 B
  float4* zbuf = (float4*)((char*)d_ws + NCOLP * C_DIM * 2);     // 4 KB zeros
  prep_kernel<<<NCOLP * C_DIM / 256 + 1, 256, 0, stream>>>(wp, bt, zbuf);
  conv_kernel<<<32 * (S_DIM / M_OUT), 256, 0, stream>>>(x, bt, (const float*)zbuf,
                                                        (float*)d_out);
}